// Round 1
// baseline (11792.672 us; speedup 1.0000x reference)
//
#include <hip/hip_runtime.h>

#define T_DIM 64
#define N_DIM 4096
#define DL 300
#define DA 74
#define DV 35
#define DTOT 409
#define ZD 256
#define GD 1024   // 4*Z
#define FD 128

// ---------------------------------------------------------------------------
// Generic 64x64-tile fp32 GEMM over 3 independent parameter sets (gridDim.z).
// C = A1 @ W1^T [+ A2 @ W2^T] + b1 [+ b2], optional relu.
// A row-major (lda), W row-major (cols x K, ld = K), C row-major (ldc).
// ---------------------------------------------------------------------------
struct GemmP {
    const float* A1[3];
    const float* W1[3];
    const float* A2[3];
    const float* W2[3];
    const float* b1[3];
    const float* b2[3];
    float*       C[3];
    int K1[3];
    int lda1;
    int K2;      // uniform; 0 = no second segment (A2 lda == K2, W2 ld == K2)
    int ldc;
    int relu;
};

__device__ __forceinline__ void mac16(const float (&As)[16][64], const float (&Ws)[16][64],
                                      int tx, int ty, float (&acc)[4][4]) {
#pragma unroll
    for (int k = 0; k < 16; ++k) {
        float4 av = *reinterpret_cast<const float4*>(&As[k][ty * 4]);
        float4 bv = *reinterpret_cast<const float4*>(&Ws[k][tx * 4]);
        float a[4] = {av.x, av.y, av.z, av.w};
        float b[4] = {bv.x, bv.y, bv.z, bv.w};
#pragma unroll
        for (int i = 0; i < 4; ++i)
#pragma unroll
            for (int j = 0; j < 4; ++j)
                acc[i][j] = fmaf(a[i], b[j], acc[i][j]);
    }
}

__global__ __launch_bounds__(256) void gemm3_kernel(GemmP p) {
    const int m = blockIdx.z;
    const float* __restrict__ A1 = p.A1[m];
    const float* __restrict__ W1 = p.W1[m];
    const int K1 = p.K1[m];
    float* __restrict__ C = p.C[m];
    const int row0 = blockIdx.x * 64;
    const int col0 = blockIdx.y * 64;

    __shared__ __align__(16) float As[16][64];
    __shared__ __align__(16) float Ws[16][64];

    const int tid = threadIdx.x;
    const int tx = tid & 15, ty = tid >> 4;
    float acc[4][4] = {};

    // segment 1 (bounds-checked K)
    for (int k0 = 0; k0 < K1; k0 += 16) {
#pragma unroll
        for (int i = 0; i < 4; ++i) {
            int e = tid * 4 + i;
            int r = e >> 4, k = e & 15;
            int kk = k0 + k;
            As[k][r] = (kk < K1) ? A1[(size_t)(row0 + r) * p.lda1 + kk] : 0.f;
            Ws[k][r] = (kk < K1) ? W1[(size_t)(col0 + r) * K1 + kk] : 0.f;
        }
        __syncthreads();
        mac16(As, Ws, tx, ty, acc);
        __syncthreads();
    }

    // segment 2 (K2 multiple of 16, no bounds checks)
    if (p.K2 > 0) {
        const float* __restrict__ A2 = p.A2[m];
        const float* __restrict__ W2 = p.W2[m];
        const int K2 = p.K2;
        for (int k0 = 0; k0 < K2; k0 += 16) {
#pragma unroll
            for (int i = 0; i < 4; ++i) {
                int e = tid * 4 + i;
                int r = e >> 4, k = e & 15;
                As[k][r] = A2[(size_t)(row0 + r) * K2 + k0 + k];
                Ws[k][r] = W2[(size_t)(col0 + r) * K2 + k0 + k];
            }
            __syncthreads();
            mac16(As, Ws, tx, ty, acc);
            __syncthreads();
        }
    }

    const float* __restrict__ b1 = p.b1[m];
    const float* __restrict__ b2 = p.b2[m];
#pragma unroll
    for (int i = 0; i < 4; ++i) {
        int r = row0 + ty * 4 + i;
        float v[4];
#pragma unroll
        for (int j = 0; j < 4; ++j) {
            int cc = col0 + tx * 4 + j;
            float t = acc[i][j] + b1[cc] + (b2 ? b2[cc] : 0.f);
            if (p.relu) t = fmaxf(t, 0.f);
            v[j] = t;
        }
        float4 o = make_float4(v[0], v[1], v[2], v[3]);
        *reinterpret_cast<float4*>(&C[(size_t)r * p.ldc + col0 + tx * 4]) = o;
    }
}

// ---------------------------------------------------------------------------
// LSTM pointwise: gates [3][N][1024] -> update h,c [3][N][256]
// ---------------------------------------------------------------------------
__global__ __launch_bounds__(256) void lstm_pw_kernel(const float* __restrict__ gates,
                                                      float* __restrict__ h,
                                                      float* __restrict__ c) {
    unsigned int idx = blockIdx.x * 256u + threadIdx.x;  // over 3*N*Z = 3,145,728
    const unsigned int per_m = (unsigned int)N_DIM * ZD;
    unsigned int m = idx / per_m;
    unsigned int r = idx - m * per_m;
    unsigned int n = r >> 8;
    unsigned int z = r & 255u;
    const float* g = gates + ((size_t)m * N_DIM + n) * GD;
    float gi = g[z], gf = g[ZD + z], gg = g[2 * ZD + z], go = g[3 * ZD + z];
    float i_ = 1.f / (1.f + __expf(-gi));
    float f_ = 1.f / (1.f + __expf(-gf));
    float g_ = tanhf(gg);
    float o_ = 1.f / (1.f + __expf(-go));
    float cc = c[idx];
    cc = f_ * cc + i_ * g_;
    c[idx] = cc;
    h[idx] = o_ * tanhf(cc);
}

// ---------------------------------------------------------------------------
// Split x (T,N,409) into the three output slices
// ---------------------------------------------------------------------------
__global__ __launch_bounds__(256) void split_kernel(const float* __restrict__ x,
                                                    float* __restrict__ out_l,
                                                    float* __restrict__ out_a,
                                                    float* __restrict__ out_v) {
    const unsigned int total = (unsigned int)T_DIM * N_DIM * DTOT;  // 107,216,896
    unsigned int stride = gridDim.x * 256u;
    for (unsigned int s = blockIdx.x * 256u + threadIdx.x; s < total; s += stride) {
        unsigned int row = s / DTOT;
        unsigned int d = s - row * DTOT;
        float v = x[s];
        if (d < DL)            out_l[(size_t)row * DL + d] = v;
        else if (d < DL + DA)  out_a[(size_t)row * DA + (d - DL)] = v;
        else                   out_v[(size_t)row * DV + (d - DL - DA)] = v;
    }
}

// ---------------------------------------------------------------------------
// y[n] = dot(fs[n,:384], Wy) + by  — one wave per row
// ---------------------------------------------------------------------------
__global__ __launch_bounds__(256) void y_kernel(const float* __restrict__ fs,
                                                const float* __restrict__ Wy,
                                                const float* __restrict__ by,
                                                float* __restrict__ y) {
    unsigned int wave = (blockIdx.x * 256u + threadIdx.x) >> 6;
    unsigned int lane = threadIdx.x & 63u;
    if (wave >= N_DIM) return;
    const float* row = fs + (size_t)wave * 3 * FD;
    float s = 0.f;
    for (unsigned int j = lane; j < 3 * FD; j += 64) s += row[j] * Wy[j];
#pragma unroll
    for (int off = 32; off; off >>= 1) s += __shfl_down(s, off);
    if (lane == 0) y[wave] = s + by[0];
}

extern "C" void kernel_launch(void* const* d_in, const int* in_sizes, int n_in,
                              void* d_out, int out_size, void* d_ws, size_t ws_size,
                              hipStream_t stream) {
    const float* x = (const float*)d_in[0];
    const float *W_ih[3], *W_hh[3], *b_ih[3], *b_hh[3], *Wfc[3], *bfc[3],
                *Wh1[3], *bh1[3], *Wh2[3], *bh2[3];
    for (int m = 0; m < 3; ++m) {
        const int b = 1 + m * 10;
        W_ih[m] = (const float*)d_in[b + 0];
        W_hh[m] = (const float*)d_in[b + 1];
        b_ih[m] = (const float*)d_in[b + 2];
        b_hh[m] = (const float*)d_in[b + 3];
        Wfc[m]  = (const float*)d_in[b + 4];
        bfc[m]  = (const float*)d_in[b + 5];
        Wh1[m]  = (const float*)d_in[b + 6];
        bh1[m]  = (const float*)d_in[b + 7];
        Wh2[m]  = (const float*)d_in[b + 8];
        bh2[m]  = (const float*)d_in[b + 9];
    }
    const float* Wy = (const float*)d_in[31];
    const float* by = (const float*)d_in[32];

    // outputs
    float* out   = (float*)d_out;
    float* out_l = out;
    float* out_a = out_l + (size_t)T_DIM * N_DIM * DL;
    float* out_v = out_a + (size_t)T_DIM * N_DIM * DA;
    float* out_y = out_v + (size_t)T_DIM * N_DIM * DV;

    // workspace layout (floats)
    const size_t NZ = (size_t)N_DIM * ZD;       // 1,048,576
    const size_t NG = (size_t)N_DIM * GD;       // 4,194,304
    const size_t NF = (size_t)N_DIM * FD;       // 524,288
    float* ws   = (float*)d_ws;
    float* h    = ws;                  // 3*NZ
    float* c    = h + 3 * NZ;          // 3*NZ
    float* gates = c + 3 * NZ;         // 3*NG
    float* zbuf = gates + 3 * NG;      // 3*NZ
    float* f1   = zbuf + 3 * NZ;       // 3*NF
    float* fs   = f1 + 3 * NF;         // 3*NF
    size_t need = (3 * NZ * 3 + 3 * NG + 3 * NF * 2) * sizeof(float);
    if (ws_size < need) return;  // insufficient scratch — fail safely

    const int   dm[3]  = {DL, DA, DV};
    const int   off[3] = {0, DL, DL + DA};

    // h,c = 0
    hipMemsetAsync(d_ws, 0, 2 * 3 * NZ * sizeof(float), stream);

    // output slice copies
    split_kernel<<<4096, 256, 0, stream>>>(x, out_l, out_a, out_v);

    // recurrent loop
    for (int t = 0; t < T_DIM; ++t) {
        GemmP p{};
        const float* xt = x + (size_t)t * N_DIM * DTOT;
        for (int m = 0; m < 3; ++m) {
            p.A1[m] = xt + off[m];
            p.W1[m] = W_ih[m];
            p.K1[m] = dm[m];
            p.A2[m] = h + m * NZ;
            p.W2[m] = W_hh[m];
            p.b1[m] = b_ih[m];
            p.b2[m] = b_hh[m];
            p.C[m]  = gates + m * NG;
        }
        p.lda1 = DTOT;
        p.K2 = ZD;
        p.ldc = GD;
        p.relu = 0;
        gemm3_kernel<<<dim3(N_DIM / 64, GD / 64, 3), 256, 0, stream>>>(p);
        lstm_pw_kernel<<<(3 * N_DIM * ZD) / 256, 256, 0, stream>>>(gates, h, c);
    }

    // z = h @ Wfc^T + bfc
    {
        GemmP p{};
        for (int m = 0; m < 3; ++m) {
            p.A1[m] = h + m * NZ;  p.W1[m] = Wfc[m]; p.K1[m] = ZD;
            p.b1[m] = bfc[m];      p.b2[m] = nullptr;
            p.C[m]  = zbuf + m * NZ;
        }
        p.lda1 = ZD; p.K2 = 0; p.ldc = ZD; p.relu = 0;
        gemm3_kernel<<<dim3(N_DIM / 64, ZD / 64, 3), 256, 0, stream>>>(p);
    }
    // f1 = relu(z @ Wh1^T + bh1)
    {
        GemmP p{};
        for (int m = 0; m < 3; ++m) {
            p.A1[m] = zbuf + m * NZ; p.W1[m] = Wh1[m]; p.K1[m] = ZD;
            p.b1[m] = bh1[m];        p.b2[m] = nullptr;
            p.C[m]  = f1 + m * NF;
        }
        p.lda1 = ZD; p.K2 = 0; p.ldc = FD; p.relu = 1;
        gemm3_kernel<<<dim3(N_DIM / 64, FD / 64, 3), 256, 0, stream>>>(p);
    }
    // fs[:, m*128:(m+1)*128] = relu(f1 @ Wh2^T + bh2)
    {
        GemmP p{};
        for (int m = 0; m < 3; ++m) {
            p.A1[m] = f1 + m * NF; p.W1[m] = Wh2[m]; p.K1[m] = FD;
            p.b1[m] = bh2[m];      p.b2[m] = nullptr;
            p.C[m]  = fs + m * FD;
        }
        p.lda1 = FD; p.K2 = 0; p.ldc = 3 * FD; p.relu = 1;
        gemm3_kernel<<<dim3(N_DIM / 64, FD / 64, 3), 256, 0, stream>>>(p);
    }
    // y
    y_kernel<<<(N_DIM * 64) / 256, 256, 0, stream>>>(fs, Wy, by, out_y);
}

// Round 2
// 4023.824 us; speedup vs baseline: 2.9307x; 2.9307x over previous
//
#include <hip/hip_runtime.h>

typedef __attribute__((ext_vector_type(8))) short short8;
typedef __attribute__((ext_vector_type(4))) float f32x4;
typedef unsigned short ushort_t;

#define T_DIM 64
#define N_DIM 4096
#define DL 300
#define DA 74
#define DV 35
#define DTOT 409
#define ZD 256
#define GD 1024
#define FD 128
#define KP1_L 320
#define KP1_A 96
#define KP1_V 64
#define KT_L (KP1_L + 256)   // 576
#define KT_A (KP1_A + 256)   // 352
#define KT_V (KP1_V + 256)   // 320

__device__ __forceinline__ ushort_t f2bf(float v) {
    unsigned u = __float_as_uint(v);
    u += 0x7fffu + ((u >> 16) & 1u);
    return (ushort_t)(u >> 16);
}

// ---------------------------------------------------------------------------
// Weight conversion: Wc[m] = [W_ih | pad0 | W_hh] per output row, bf16, K padded
// ---------------------------------------------------------------------------
struct WConvP {
    const float* Wih[3];
    const float* Whh[3];
    ushort_t* wc[3];
    int d[3];
    int kp1[3];
    int kt[3];
};
__global__ __launch_bounds__(256) void wconv_kernel(WConvP p) {
    unsigned e = blockIdx.x * 256u + threadIdx.x;
    const unsigned n0 = 1024u * KT_L, n1 = n0 + 1024u * KT_A, n2 = n1 + 1024u * KT_V;
    int m;
    unsigned rel;
    if (e < n0) { m = 0; rel = e; }
    else if (e < n1) { m = 1; rel = e - n0; }
    else if (e < n2) { m = 2; rel = e - n1; }
    else return;
    int kt = p.kt[m];
    unsigned row = rel / (unsigned)kt;
    unsigned k = rel - row * (unsigned)kt;
    float v = 0.f;
    if ((int)k < p.d[m]) v = p.Wih[m][(size_t)row * p.d[m] + k];
    else if ((int)k >= p.kp1[m]) v = p.Whh[m][(size_t)row * 256u + (k - p.kp1[m])];
    p.wc[m][(size_t)row * kt + k] = f2bf(v);
}

// ---------------------------------------------------------------------------
// x conversion: padded bf16 slices for nt timesteps starting at t0
// element space: nt*N*480, 480 = 320+96+64
// ---------------------------------------------------------------------------
struct XConvP {
    const float* x;
    ushort_t* xb[3];
    int t0;
};
__global__ __launch_bounds__(256) void xconv_kernel(XConvP p) {
    unsigned e = blockIdx.x * 256u + threadIdx.x;
    unsigned row = e / 480u;
    unsigned k480 = e - row * 480u;
    int m, dm, off;
    unsigned k, kp1;
    if (k480 < 320u)      { m = 0; k = k480;        kp1 = KP1_L; dm = DL; off = 0; }
    else if (k480 < 416u) { m = 1; k = k480 - 320u; kp1 = KP1_A; dm = DA; off = DL; }
    else                  { m = 2; k = k480 - 416u; kp1 = KP1_V; dm = DV; off = DL + DA; }
    float v = 0.f;
    if ((int)k < dm) v = p.x[((size_t)p.t0 * N_DIM + row) * DTOT + off + k];
    ushort_t* xb = (m == 0) ? p.xb[0] : (m == 1) ? p.xb[1] : p.xb[2];
    xb[(size_t)row * kp1 + k] = f2bf(v);
}

// ---------------------------------------------------------------------------
// Fused LSTM step: gates = [x_t|h] @ Wc^T (MFMA bf16) -> pointwise -> h(bf16), c(f32)
// Block: 256 threads = 4 waves; tile 64 rows x 64 z (all 4 gates).
// Wave w, colfrag cf -> W rows cf*256 + z0 + 16w + (lane&15): each lane ends
// with all 4 gates for its (n,z) in acc[rf][0..3][reg]. No cross-lane needed.
// ---------------------------------------------------------------------------
struct StepP {
    const ushort_t* xb[3];
    const ushort_t* wc[3];
    const float* bih[3];
    const float* bhh[3];
    ushort_t* h;
    float* c;
    int kp1[3];
    int kt[3];
};
__global__ __launch_bounds__(256) void lstm_step_kernel(StepP p) {
    const int m = blockIdx.z;
    const ushort_t* __restrict__ xb = p.xb[m];
    const ushort_t* __restrict__ wc = p.wc[m];
    const int kp1 = p.kp1[m], kt = p.kt[m];
    ushort_t* __restrict__ h = p.h + (size_t)m * N_DIM * ZD;
    float* __restrict__ c = p.c + (size_t)m * N_DIM * ZD;
    const int row0 = blockIdx.x * 64, z0 = blockIdx.y * 64;
    const int tid = threadIdx.x, w = tid >> 6;
    const int lane = tid & 63, ln = lane & 15, lg = lane >> 4;

    f32x4 acc[4][4] = {};

    const ushort_t* wrow[4];
#pragma unroll
    for (int cf = 0; cf < 4; ++cf)
        wrow[cf] = wc + (size_t)(cf * ZD + z0 + w * 16 + ln) * kt + lg * 8;

    for (int k0 = 0; k0 < kt; k0 += 32) {
        short8 a[4], b[4];
        if (k0 < kp1) {
#pragma unroll
            for (int rf = 0; rf < 4; ++rf)
                a[rf] = *reinterpret_cast<const short8*>(
                    xb + (size_t)(row0 + rf * 16 + ln) * kp1 + k0 + lg * 8);
        } else {
#pragma unroll
            for (int rf = 0; rf < 4; ++rf)
                a[rf] = *reinterpret_cast<const short8*>(
                    h + (size_t)(row0 + rf * 16 + ln) * ZD + (k0 - kp1) + lg * 8);
        }
#pragma unroll
        for (int cf = 0; cf < 4; ++cf)
            b[cf] = *reinterpret_cast<const short8*>(wrow[cf] + k0);
#pragma unroll
        for (int rf = 0; rf < 4; ++rf)
#pragma unroll
            for (int cf = 0; cf < 4; ++cf)
                acc[rf][cf] = __builtin_amdgcn_mfma_f32_16x16x32_bf16(
                    a[rf], b[cf], acc[rf][cf], 0, 0, 0);
    }

    // epilogue: pointwise LSTM cell, all gates in-lane
    const int z = z0 + w * 16 + ln;
    const float* __restrict__ bih = p.bih[m];
    const float* __restrict__ bhh = p.bhh[m];
    const float bi = bih[z] + bhh[z];
    const float bf_ = bih[ZD + z] + bhh[ZD + z];
    const float bg = bih[2 * ZD + z] + bhh[2 * ZD + z];
    const float bo = bih[3 * ZD + z] + bhh[3 * ZD + z];
#pragma unroll
    for (int rf = 0; rf < 4; ++rf) {
#pragma unroll
        for (int reg = 0; reg < 4; ++reg) {
            const int n = row0 + rf * 16 + lg * 4 + reg;
            const size_t idx = (size_t)n * ZD + z;
            float gi = acc[rf][0][reg] + bi;
            float gf = acc[rf][1][reg] + bf_;
            float gg = acc[rf][2][reg] + bg;
            float go = acc[rf][3][reg] + bo;
            float i_ = 1.f / (1.f + __expf(-gi));
            float f_ = 1.f / (1.f + __expf(-gf));
            float g_ = 1.f - 2.f / (1.f + __expf(2.f * gg));
            float o_ = 1.f / (1.f + __expf(-go));
            float cc = f_ * c[idx] + i_ * g_;
            c[idx] = cc;
            float hh = o_ * (1.f - 2.f / (1.f + __expf(2.f * cc)));
            h[idx] = f2bf(hh);
        }
    }
}

// ---------------------------------------------------------------------------
// h bf16 -> f32
// ---------------------------------------------------------------------------
__global__ __launch_bounds__(256) void h2f_kernel(const ushort_t* __restrict__ h,
                                                  float* __restrict__ hf) {
    unsigned i = blockIdx.x * 256u + threadIdx.x;
    hf[i] = __uint_as_float(((unsigned)h[i]) << 16);
}

// ---------------------------------------------------------------------------
// fp32 tiled GEMM for the small head layers (unchanged from round 1)
// ---------------------------------------------------------------------------
struct GemmP {
    const float* A1[3];
    const float* W1[3];
    const float* b1[3];
    float* C[3];
    int K1[3];
    int lda1;
    int ldc;
    int relu;
};

__device__ __forceinline__ void mac16(const float (&As)[16][64], const float (&Ws)[16][64],
                                      int tx, int ty, float (&acc)[4][4]) {
#pragma unroll
    for (int k = 0; k < 16; ++k) {
        float4 av = *reinterpret_cast<const float4*>(&As[k][ty * 4]);
        float4 bv = *reinterpret_cast<const float4*>(&Ws[k][tx * 4]);
        float a[4] = {av.x, av.y, av.z, av.w};
        float b[4] = {bv.x, bv.y, bv.z, bv.w};
#pragma unroll
        for (int i = 0; i < 4; ++i)
#pragma unroll
            for (int j = 0; j < 4; ++j)
                acc[i][j] = fmaf(a[i], b[j], acc[i][j]);
    }
}

__global__ __launch_bounds__(256) void gemm3_kernel(GemmP p) {
    const int m = blockIdx.z;
    const float* __restrict__ A1 = p.A1[m];
    const float* __restrict__ W1 = p.W1[m];
    const int K1 = p.K1[m];
    float* __restrict__ C = p.C[m];
    const int row0 = blockIdx.x * 64;
    const int col0 = blockIdx.y * 64;

    __shared__ __align__(16) float As[16][64];
    __shared__ __align__(16) float Ws[16][64];

    const int tid = threadIdx.x;
    const int tx = tid & 15, ty = tid >> 4;
    float acc[4][4] = {};

    for (int k0 = 0; k0 < K1; k0 += 16) {
#pragma unroll
        for (int i = 0; i < 4; ++i) {
            int e = tid * 4 + i;
            int r = e >> 4, k = e & 15;
            int kk = k0 + k;
            As[k][r] = (kk < K1) ? A1[(size_t)(row0 + r) * p.lda1 + kk] : 0.f;
            Ws[k][r] = (kk < K1) ? W1[(size_t)(col0 + r) * K1 + kk] : 0.f;
        }
        __syncthreads();
        mac16(As, Ws, tx, ty, acc);
        __syncthreads();
    }

    const float* __restrict__ b1 = p.b1[m];
#pragma unroll
    for (int i = 0; i < 4; ++i) {
        int r = row0 + ty * 4 + i;
        float v[4];
#pragma unroll
        for (int j = 0; j < 4; ++j) {
            int cc = col0 + tx * 4 + j;
            float t = acc[i][j] + b1[cc];
            if (p.relu) t = fmaxf(t, 0.f);
            v[j] = t;
        }
        float4 o = make_float4(v[0], v[1], v[2], v[3]);
        *reinterpret_cast<float4*>(&C[(size_t)r * p.ldc + col0 + tx * 4]) = o;
    }
}

// ---------------------------------------------------------------------------
// split x into the three output slices
// ---------------------------------------------------------------------------
__global__ __launch_bounds__(256) void split_kernel(const float* __restrict__ x,
                                                    float* __restrict__ out_l,
                                                    float* __restrict__ out_a,
                                                    float* __restrict__ out_v) {
    const unsigned total = (unsigned)T_DIM * N_DIM * DTOT;
    unsigned stride = gridDim.x * 256u;
    for (unsigned s = blockIdx.x * 256u + threadIdx.x; s < total; s += stride) {
        unsigned row = s / DTOT;
        unsigned d = s - row * DTOT;
        float v = x[s];
        if (d < DL)            out_l[(size_t)row * DL + d] = v;
        else if (d < DL + DA)  out_a[(size_t)row * DA + (d - DL)] = v;
        else                   out_v[(size_t)row * DV + (d - DL - DA)] = v;
    }
}

// ---------------------------------------------------------------------------
// y[n] = dot(fs[n,:384], Wy) + by
// ---------------------------------------------------------------------------
__global__ __launch_bounds__(256) void y_kernel(const float* __restrict__ fs,
                                                const float* __restrict__ Wy,
                                                const float* __restrict__ by,
                                                float* __restrict__ y) {
    unsigned wave = (blockIdx.x * 256u + threadIdx.x) >> 6;
    unsigned lane = threadIdx.x & 63u;
    if (wave >= N_DIM) return;
    const float* row = fs + (size_t)wave * 3 * FD;
    float s = 0.f;
    for (unsigned j = lane; j < 3 * FD; j += 64) s += row[j] * Wy[j];
#pragma unroll
    for (int off = 32; off; off >>= 1) s += __shfl_down(s, off);
    if (lane == 0) y[wave] = s + by[0];
}

extern "C" void kernel_launch(void* const* d_in, const int* in_sizes, int n_in,
                              void* d_out, int out_size, void* d_ws, size_t ws_size,
                              hipStream_t stream) {
    const float* x = (const float*)d_in[0];
    const float *W_ih[3], *W_hh[3], *b_ih[3], *b_hh[3], *Wfc[3], *bfc[3],
                *Wh1[3], *bh1[3], *Wh2[3], *bh2[3];
    for (int m = 0; m < 3; ++m) {
        const int b = 1 + m * 10;
        W_ih[m] = (const float*)d_in[b + 0];
        W_hh[m] = (const float*)d_in[b + 1];
        b_ih[m] = (const float*)d_in[b + 2];
        b_hh[m] = (const float*)d_in[b + 3];
        Wfc[m]  = (const float*)d_in[b + 4];
        bfc[m]  = (const float*)d_in[b + 5];
        Wh1[m]  = (const float*)d_in[b + 6];
        bh1[m]  = (const float*)d_in[b + 7];
        Wh2[m]  = (const float*)d_in[b + 8];
        bh2[m]  = (const float*)d_in[b + 9];
    }
    const float* Wy = (const float*)d_in[31];
    const float* by = (const float*)d_in[32];

    float* out   = (float*)d_out;
    float* out_l = out;
    float* out_a = out_l + (size_t)T_DIM * N_DIM * DL;
    float* out_v = out_a + (size_t)T_DIM * N_DIM * DA;
    float* out_y = out_v + (size_t)T_DIM * N_DIM * DV;

    const size_t NZ = (size_t)N_DIM * ZD;   // 1,048,576
    const size_t NF = (size_t)N_DIM * FD;   // 524,288

    // workspace layout (bytes, all 16B-aligned)
    char* wsb = (char*)d_ws;
    ushort_t* hbuf = (ushort_t*)wsb;                       // 3*NZ*2   = 6,291,456
    float*    cbuf = (float*)(wsb + 3 * NZ * 2);           // 3*NZ*4   = 12,582,912
    char*     wc0  = wsb + 3 * NZ * 2 + 3 * NZ * 4;
    ushort_t* wc_l = (ushort_t*)wc0;                       // 1024*KT_L
    ushort_t* wc_a = wc_l + (size_t)1024 * KT_L;
    ushort_t* wc_v = wc_a + (size_t)1024 * KT_A;
    char*     after_wc = wc0 + (size_t)1024 * (KT_L + KT_A + KT_V) * 2;
    float* hf   = (float*)after_wc;                        // 3*NZ*4
    float* zbuf = hf + 3 * NZ;                             // 3*NZ*4
    float* f1   = zbuf + 3 * NZ;                           // 3*NF*4
    float* fs   = f1 + 3 * NF;                             // 3*NF*4
    char*  xb0  = (char*)(fs + 3 * NF);

    const size_t fixed = (size_t)(xb0 - wsb);
    const size_t xb_small = (size_t)N_DIM * (KP1_L + KP1_A + KP1_V) * 2;  // 3,932,160
    const size_t xb_big   = xb_small * T_DIM;                             // 251,658,240
    if (ws_size < fixed + xb_small) return;  // cannot run safely
    const bool big = (ws_size >= fixed + xb_big);
    const int ntcap = big ? T_DIM : 1;

    ushort_t* xb_l = (ushort_t*)xb0;
    ushort_t* xb_a = xb_l + (size_t)ntcap * N_DIM * KP1_L;
    ushort_t* xb_v = xb_a + (size_t)ntcap * N_DIM * KP1_A;

    // zero h, c
    hipMemsetAsync(wsb, 0, 3 * NZ * 2 + 3 * NZ * 4, stream);

    // weight conversion
    {
        WConvP p{};
        for (int m = 0; m < 3; ++m) { p.Wih[m] = W_ih[m]; p.Whh[m] = W_hh[m]; }
        p.wc[0] = wc_l; p.wc[1] = wc_a; p.wc[2] = wc_v;
        p.d[0] = DL; p.d[1] = DA; p.d[2] = DV;
        p.kp1[0] = KP1_L; p.kp1[1] = KP1_A; p.kp1[2] = KP1_V;
        p.kt[0] = KT_L; p.kt[1] = KT_A; p.kt[2] = KT_V;
        wconv_kernel<<<(1024 * (KT_L + KT_A + KT_V)) / 256, 256, 0, stream>>>(p);
    }

    // output slice copies
    split_kernel<<<4096, 256, 0, stream>>>(x, out_l, out_a, out_v);

    // x conversion (all steps when workspace allows)
    if (big) {
        XConvP p{};
        p.x = x; p.xb[0] = xb_l; p.xb[1] = xb_a; p.xb[2] = xb_v; p.t0 = 0;
        xconv_kernel<<<(T_DIM * N_DIM * 480) / 256, 256, 0, stream>>>(p);
    }

    // recurrent loop
    StepP sp{};
    sp.wc[0] = wc_l; sp.wc[1] = wc_a; sp.wc[2] = wc_v;
    for (int m = 0; m < 3; ++m) { sp.bih[m] = b_ih[m]; sp.bhh[m] = b_hh[m]; }
    sp.h = hbuf; sp.c = cbuf;
    sp.kp1[0] = KP1_L; sp.kp1[1] = KP1_A; sp.kp1[2] = KP1_V;
    sp.kt[0] = KT_L; sp.kt[1] = KT_A; sp.kt[2] = KT_V;

    for (int t = 0; t < T_DIM; ++t) {
        if (!big) {
            XConvP p{};
            p.x = x; p.xb[0] = xb_l; p.xb[1] = xb_a; p.xb[2] = xb_v; p.t0 = t;
            xconv_kernel<<<(N_DIM * 480) / 256, 256, 0, stream>>>(p);
        }
        const size_t ts = big ? (size_t)t : 0;
        sp.xb[0] = xb_l + ts * N_DIM * KP1_L;
        sp.xb[1] = xb_a + ts * N_DIM * KP1_A;
        sp.xb[2] = xb_v + ts * N_DIM * KP1_V;
        lstm_step_kernel<<<dim3(N_DIM / 64, ZD / 64, 3), 256, 0, stream>>>(sp);
    }

    // h -> f32
    h2f_kernel<<<(3 * NZ) / 256, 256, 0, stream>>>(hbuf, hf);

    // z = h @ Wfc^T + bfc
    {
        GemmP p{};
        for (int m = 0; m < 3; ++m) {
            p.A1[m] = hf + m * NZ; p.W1[m] = Wfc[m]; p.K1[m] = ZD;
            p.b1[m] = bfc[m];      p.C[m] = zbuf + m * NZ;
        }
        p.lda1 = ZD; p.ldc = ZD; p.relu = 0;
        gemm3_kernel<<<dim3(N_DIM / 64, ZD / 64, 3), 256, 0, stream>>>(p);
    }
    // f1 = relu(z @ Wh1^T + bh1)
    {
        GemmP p{};
        for (int m = 0; m < 3; ++m) {
            p.A1[m] = zbuf + m * NZ; p.W1[m] = Wh1[m]; p.K1[m] = ZD;
            p.b1[m] = bh1[m];        p.C[m] = f1 + m * NF;
        }
        p.lda1 = ZD; p.ldc = FD; p.relu = 1;
        gemm3_kernel<<<dim3(N_DIM / 64, FD / 64, 3), 256, 0, stream>>>(p);
    }
    // fs[:, m*128:(m+1)*128] = relu(f1 @ Wh2^T + bh2)
    {
        GemmP p{};
        for (int m = 0; m < 3; ++m) {
            p.A1[m] = f1 + m * NF; p.W1[m] = Wh2[m]; p.K1[m] = FD;
            p.b1[m] = bh2[m];      p.C[m] = fs + m * FD;
        }
        p.lda1 = FD; p.ldc = 3 * FD; p.relu = 1;
        gemm3_kernel<<<dim3(N_DIM / 64, FD / 64, 3), 256, 0, stream>>>(p);
    }
    // y
    y_kernel<<<(N_DIM * 64) / 256, 256, 0, stream>>>(fs, Wy, by, out_y);
}